// Round 2
// 561.087 us; speedup vs baseline: 1.0566x; 1.0566x over previous
//
#include <hip/hip_runtime.h>
#include <math.h>

// LRN on x[16,96,224,224] fp32.
// out = x * (2 + 1e-4 * boxfilter5x5(sum_c x^2))^(-0.75)
//
// Round 2 structure: 4 kernels, channel-split for occupancy.
//   A  : part[g][b,h,w] = sum_{c in group g} x^2   (4 groups of 24 ch -> 3136 blocks)
//   A2a: s = sum_g part[g]                          (L2/L3-resident, tiny)
//   A2b: sc = (2+1e-4*box5x5(s))^-0.75              (L2-resident, tiny)
//   B  : out = x * sc                               (channel-split x4 -> 3136 blocks)
//
// Rationale: round-0 A/B launched only 784 blocks (~3 waves/SIMD, ~4 loads in
// flight vs ~900cy HBM latency) -> latency-bound at 1.6-3.3 TB/s. 4x block
// split + unroll 8 raises MLP/occupancy toward the 6.3 TB/s ceiling.
// v2 fix: __builtin_nontemporal_* needs clang ext_vector_type, not float4.

#define BB 16
#define CC 96
#define HH 224
#define WW 224
#define HW (HH * WW)          // 50176
#define CHW (CC * HW)         // 4816896
#define NPIX (BB * HW)        // 802816
#define W4 (WW / 4)           // 56
#define NCOL (BB * HH * W4)   // 200704 float4 columns per channel-plane
#define CG 4                  // channel groups
#define CPG (CC / CG)         // 24 channels per group

typedef float v4f __attribute__((ext_vector_type(4)));

__global__ __launch_bounds__(256) void lrn_sqsum(const float* __restrict__ x,
                                                 float* __restrict__ part) {
    int t  = blockIdx.x * 256 + threadIdx.x;
    if (t >= NCOL) return;
    int cg = blockIdx.y;
    int w4 = t % W4;
    int bh = t / W4;              // b*HH + h
    int b  = bh / HH;
    int h  = bh % HH;
    size_t idx = (((size_t)b * CHW + (size_t)h * WW) >> 2) + w4
               + (size_t)cg * CPG * (HW / 4);   // float4 index
    const v4f* xp = (const v4f*)x;
    v4f acc = (v4f)(0.f);
#pragma unroll 8
    for (int c = 0; c < CPG; ++c) {
        v4f v = __builtin_nontemporal_load(&xp[idx + (size_t)c * (HW / 4)]);
        acc += v * v;
    }
    ((v4f*)part)[(size_t)cg * NCOL + t] = acc;
}

__global__ __launch_bounds__(256) void lrn_sum4(const float* __restrict__ part,
                                                float* __restrict__ s) {
    int t = blockIdx.x * 256 + threadIdx.x;
    if (t >= NCOL) return;
    const v4f* p = (const v4f*)part;
    v4f a = p[t];
    v4f b = p[(size_t)NCOL + t];
    v4f c = p[(size_t)2 * NCOL + t];
    v4f d = p[(size_t)3 * NCOL + t];
    ((v4f*)s)[t] = (a + b) + (c + d);
}

__global__ __launch_bounds__(256) void lrn_scale(const float* __restrict__ s,
                                                 float* __restrict__ sc) {
    int t = blockIdx.x * 256 + threadIdx.x;
    if (t >= NPIX) return;
    int w  = t % WW;
    int bh = t / WW;              // b*HH + h
    int h  = bh % HH;
    float y = 0.f;
#pragma unroll
    for (int dh = -2; dh <= 2; ++dh) {
        int hh = h + dh;
        if (hh < 0 || hh >= HH) continue;          // zero padding (SAME)
        const float* row = s + (size_t)(bh + dh) * WW;  // same b guaranteed by hh bounds
#pragma unroll
        for (int dw = -2; dw <= 2; ++dw) {
            int ww = w + dw;
            if (ww >= 0 && ww < WW) y += row[ww];
        }
    }
    sc[t] = powf(2.0f + 1e-4f * y, -0.75f);
}

__global__ __launch_bounds__(256) void lrn_norm(const float* __restrict__ x,
                                                const float* __restrict__ sc,
                                                float* __restrict__ out) {
    int t  = blockIdx.x * 256 + threadIdx.x;
    if (t >= NCOL) return;
    int cg = blockIdx.y;
    int w4 = t % W4;
    int bh = t / W4;
    int b  = bh / HH;
    int h  = bh % HH;
    v4f scv = ((const v4f*)sc)[t];
    size_t idx = (((size_t)b * CHW + (size_t)h * WW) >> 2) + w4
               + (size_t)cg * CPG * (HW / 4);
    const v4f* xp = (const v4f*)x;
    v4f* op = (v4f*)out;
#pragma unroll 8
    for (int c = 0; c < CPG; ++c) {
        size_t i = idx + (size_t)c * (HW / 4);
        v4f v = __builtin_nontemporal_load(&xp[i]);
        __builtin_nontemporal_store(v * scv, &op[i]);
    }
}

extern "C" void kernel_launch(void* const* d_in, const int* in_sizes, int n_in,
                              void* d_out, int out_size, void* d_ws, size_t ws_size,
                              hipStream_t stream) {
    const float* x = (const float*)d_in[0];
    float* out  = (float*)d_out;
    float* part = (float*)d_ws;               // CG*NPIX floats = 12.8 MB
    float* s    = part + (size_t)CG * NPIX;   // NPIX floats   =  3.2 MB
    float* sc   = s + NPIX;                   // NPIX floats   =  3.2 MB (ws needs 19.3 MB)

    lrn_sqsum<<<dim3((NCOL + 255) / 256, CG), 256, 0, stream>>>(x, part);
    lrn_sum4 <<<(NCOL + 255) / 256, 256, 0, stream>>>(part, s);
    lrn_scale<<<(NPIX + 255) / 256, 256, 0, stream>>>(s, sc);
    lrn_norm <<<dim3((NCOL + 255) / 256, CG), 256, 0, stream>>>(x, sc, out);
}